// Round 1
// baseline (10010.229 us; speedup 1.0000x reference)
//
#include <hip/hip_runtime.h>

typedef __attribute__((ext_vector_type(8))) short short8;
typedef __attribute__((ext_vector_type(4))) float f32x4;
typedef __attribute__((ext_vector_type(4))) unsigned int uint4v;
typedef unsigned short u16;

#define DEVI static __device__ __forceinline__

constexpr int TTm = 64;     // seq len (src & tgt)
constexpr int BBm = 64;     // batch
constexpr int EEm = 512;    // embed dim
constexpr int HHm = 1024;   // hidden
constexpr int GGm = 4096;   // 4*H
constexpr int VVm = 32000;  // vocab
constexpr int TDm = 63;     // decoder steps

// ---------- small helpers ----------
DEVI u16 f2b(float f) {  // fp32 -> bf16 RNE
  unsigned u = __builtin_bit_cast(unsigned, f);
  return (u16)((u + 0x7fffu + ((u >> 16) & 1u)) >> 16);
}
DEVI float b2f(u16 h) { return __builtin_bit_cast(float, (unsigned)h << 16); }
DEVI float sigm(float x) { return 1.0f / (1.0f + __expf(-x)); }
DEVI float tanh_(float x) { return 1.0f - 2.0f / (1.0f + __expf(2.0f * x)); }

DEVI short8 cvt8(const float* p) {
  f32x4 x0 = *(const f32x4*)p;
  f32x4 x1 = *(const f32x4*)(p + 4);
  short8 r;
#pragma unroll
  for (int i = 0; i < 4; ++i) { r[i] = (short)f2b(x0[i]); r[i + 4] = (short)f2b(x1[i]); }
  return r;
}
// stage 32 contiguous K elements into LDS row (dst must be 16B aligned)
DEVI void stage32_f32(short* dst, const float* src) {
#pragma unroll
  for (int i = 0; i < 4; ++i) *(short8*)&dst[i * 8] = cvt8(src + i * 8);
}
DEVI void stage32_b16(short* dst, const u16* src) {
#pragma unroll
  for (int i = 0; i < 4; ++i) *(uint4v*)&dst[i * 8] = *(const uint4v*)(src + i * 8);
}

// one BK=64 step of a 64x64 tile; 2 waves, wave wv owns cols [wv*32, wv*32+32)
// LDS row stride = 72 shorts (144B: 16B-aligned, <=2-way bank aliasing)
DEVI void mfma_bk64(const short* As, const short* Bs, f32x4 acc[4][2], int wv, int ln) {
  const int l15 = ln & 15;
#pragma unroll
  for (int ks = 0; ks < 64; ks += 32) {
    const int kq = ks + ((ln >> 4) << 3);
    short8 b0 = *(const short8*)&Bs[(wv * 32 + l15) * 72 + kq];
    short8 b1 = *(const short8*)&Bs[(wv * 32 + 16 + l15) * 72 + kq];
#pragma unroll
    for (int mt = 0; mt < 4; ++mt) {
      short8 a = *(const short8*)&As[(mt * 16 + l15) * 72 + kq];
      acc[mt][0] = __builtin_amdgcn_mfma_f32_16x16x32_bf16(a, b0, acc[mt][0], 0, 0, 0);
      acc[mt][1] = __builtin_amdgcn_mfma_f32_16x16x32_bf16(a, b1, acc[mt][1], 0, 0, 0);
    }
  }
}

// ---------- setup ----------
__global__ void k_zero(uint4v* p, int n16) {
  int i = blockIdx.x * blockDim.x + threadIdx.x;
  uint4v z = {0u, 0u, 0u, 0u};
  for (; i < n16; i += gridDim.x * blockDim.x) p[i] = z;
}

__global__ void k_cvt_all(const float* Wihf, const float* Wihb, const float* Whhf,
                          const float* Whhb, const float* Wihd, const float* Whhd,
                          const float* Watt, const float* Whp, const float* Wcp,
                          const float* Wcomb, const float* Wvoc,
                          u16* o_ihf, u16* o_ihb, u16* o_hhf, u16* o_hhb, u16* o_cat,
                          u16* o_att, u16* o_hp, u16* o_cp, u16* o_comb, u16* o_voc) {
  long i = (long)blockIdx.x * blockDim.x + threadIdx.x;
  const long stride = (long)gridDim.x * blockDim.x;
  for (; i < 65273856L; i += stride) {
    long r = i;
    if (r < 2097152) { o_ihf[r] = f2b(Wihf[r]); continue; } r -= 2097152;
    if (r < 2097152) { o_ihb[r] = f2b(Wihb[r]); continue; } r -= 2097152;
    if (r < 4194304) { o_hhf[r] = f2b(Whhf[r]); continue; } r -= 4194304;
    if (r < 4194304) { o_hhb[r] = f2b(Whhb[r]); continue; } r -= 4194304;
    if (r < 10485760) {  // W_cat row g = [W_ih_d[g][0:1536] | W_hh_d[g][0:1024]]
      long g = r / 2560, c = r % 2560;
      o_cat[r] = f2b(c < 1536 ? Wihd[g * 1536 + c] : Whhd[g * 1024 + (c - 1536)]);
      continue;
    } r -= 10485760;
    if (r < 2097152) { o_att[r] = f2b(Watt[r]); continue; } r -= 2097152;
    if (r < 2097152) { o_hp[r] = f2b(Whp[r]); continue; } r -= 2097152;
    if (r < 2097152) { o_cp[r] = f2b(Wcp[r]); continue; } r -= 2097152;
    if (r < 3145728) { o_comb[r] = f2b(Wcomb[r]); continue; } r -= 3145728;
    o_voc[r] = f2b(Wvoc[r]);
  }
}

// ---------- encoder input-precompute: pre = x@W_ih^T + b_ih + b_hh ----------
__global__ __launch_bounds__(128) void k_pre_enc(
    const int* src_tok, const float* emb, const u16* Wf, const u16* Wb,
    const float* bihf, const float* bhhf, const float* bihb, const float* bhhb,
    u16* pre_f, u16* pre_b) {
  __shared__ short As[64 * 72], Bs[64 * 72];
  const int rt = blockIdx.x, ct = blockIdx.y, dir = blockIdx.z;
  const u16* W = dir ? Wb : Wf;
  const float* bi = dir ? bihb : bihf;
  const float* bh = dir ? bhhb : bhhf;
  u16* pre = dir ? pre_b : pre_f;
  const int tid = threadIdx.x, wv = tid >> 6, sr = tid & 63, seg = tid >> 6;
  const int token = src_tok[rt * 64 + sr];
  const float* arow = emb + (long)token * EEm;
  const u16* brow = W + (long)(ct * 64 + sr) * EEm;
  f32x4 acc[4][2] = {};
  for (int k0 = 0; k0 < EEm; k0 += 64) {
    __syncthreads();
    stage32_f32(&As[sr * 72 + seg * 32], arow + k0 + seg * 32);
    stage32_b16(&Bs[sr * 72 + seg * 32], brow + k0 + seg * 32);
    __syncthreads();
    mfma_bk64(As, Bs, acc, wv, sr);
  }
  const int l15 = sr & 15, q = sr >> 4;
#pragma unroll
  for (int nt = 0; nt < 2; ++nt) {
    const int col = ct * 64 + wv * 32 + nt * 16 + l15;
    const float bias = bi[col] + bh[col];
#pragma unroll
    for (int mt = 0; mt < 4; ++mt)
#pragma unroll
      for (int r = 0; r < 4; ++r)
        pre[(long)(rt * 64 + mt * 16 + q * 4 + r) * GGm + col] = f2b(acc[mt][nt][r] + bias);
  }
}

// ---------- one encoder time step (both directions): gates GEMM + LSTM cell ----------
__global__ __launch_bounds__(128) void k_enc_step(
    const u16* Whhf, const u16* Whhb, const u16* pre_f, const u16* pre_b,
    const int* lens, u16* h_f, u16* h_b, float* c_f, float* c_b,
    u16* ench, int s) {
  __shared__ short As[64 * 72], Bs[64 * 72];
  __shared__ float gsh[64 * 65];
  __shared__ u16 psh[64 * 72];
  const int dir = blockIdx.x >> 6, jt = blockIdx.x & 63, j0 = jt * 16;
  const int t = dir ? (63 - s) : s;
  const u16* Whh = dir ? Whhb : Whhf;
  const u16* pre = dir ? pre_b : pre_f;
  u16* hbase = dir ? h_b : h_f;
  const u16* hcur = hbase + (s & 1) * (BBm * HHm);
  u16* hnxt = hbase + ((s & 1) ^ 1) * (BBm * HHm);
  float* cst = dir ? c_b : c_f;
  const int tid = threadIdx.x, wv = tid >> 6, sr = tid & 63, seg = tid >> 6;
  const int colg = (sr >> 4) * HHm + j0 + (sr & 15);  // weight row for local col sr
  const u16* brow = Whh + (long)colg * HHm;
  const u16* arow = hcur + sr * HHm;
  f32x4 acc[4][2] = {};
  for (int k0 = 0; k0 < HHm; k0 += 64) {
    __syncthreads();
    stage32_b16(&As[sr * 72 + seg * 32], arow + k0 + seg * 32);
    stage32_b16(&Bs[sr * 72 + seg * 32], brow + k0 + seg * 32);
    __syncthreads();
    mfma_bk64(As, Bs, acc, wv, sr);
  }
  __syncthreads();
  const int l15 = sr & 15, q = sr >> 4;
#pragma unroll
  for (int nt = 0; nt < 2; ++nt)
#pragma unroll
    for (int mt = 0; mt < 4; ++mt)
#pragma unroll
      for (int r = 0; r < 4; ++r)
        gsh[(mt * 16 + q * 4 + r) * 65 + wv * 32 + nt * 16 + l15] = acc[mt][nt][r];
  // stage pre[t] slice (4 gates x 16 j per batch row)
  const long preBase = (long)t * BBm * GGm;
#pragma unroll
  for (int i = 0; i < 2; ++i) {
    int run = tid * 2 + i, b = run >> 2, gate = run & 3;
    const u16* srcp = pre + preBase + (long)b * GGm + gate * HHm + j0;
    *(uint4v*)&psh[b * 72 + gate * 16] = *(const uint4v*)srcp;
    *(uint4v*)&psh[b * 72 + gate * 16 + 8] = *(const uint4v*)(srcp + 8);
  }
  __syncthreads();
  const int jj = tid & 15, bq = tid >> 4;
#pragma unroll
  for (int u = 0; u < 8; ++u) {
    const int b = u * 8 + bq, j = j0 + jj;
    float gi = gsh[b * 65 + jj]      + b2f(psh[b * 72 + jj]);
    float gf = gsh[b * 65 + 16 + jj] + b2f(psh[b * 72 + 16 + jj]);
    float gg = gsh[b * 65 + 32 + jj] + b2f(psh[b * 72 + 32 + jj]);
    float go = gsh[b * 65 + 48 + jj] + b2f(psh[b * 72 + 48 + jj]);
    float cold = cst[b * HHm + j];
    float c2 = sigm(gf) * cold + sigm(gi) * tanh_(gg);
    float h2 = sigm(go) * tanh_(c2);
    bool m = t < lens[b];
    cst[b * HHm + j] = m ? c2 : cold;
    hnxt[b * HHm + j] = f2b(m ? h2 : b2f(hcur[b * HHm + j]));
    ench[((long)b * TTm + t) * 2048 + dir * HHm + j] = f2b(m ? h2 : 0.0f);
  }
}

// ---------- concat final encoder states ----------
__global__ void k_cat(const u16* hf, const u16* hb, const float* cf, const float* cb,
                      u16* hcat, u16* ccat) {
  int i = blockIdx.x * blockDim.x + threadIdx.x;  // 65536
  int b = i >> 10, k = i & 1023;
  hcat[b * 2048 + k] = hf[i];
  hcat[b * 2048 + 1024 + k] = hb[i];
  ccat[b * 2048 + k] = f2b(cf[i]);
  ccat[b * 2048 + 1024 + k] = f2b(cb[i]);
}

// ---------- plain NT GEMM: C[M x (gridDim.y*64)] = A(bf16) * B(bf16)^T ----------
template <bool OUTB16>
__global__ __launch_bounds__(128) void k_gemm_plain(const u16* A, const u16* Bm,
                                                    void* C, int K) {
  __shared__ short As[64 * 72], Bs[64 * 72];
  const int rt = blockIdx.x, ct = blockIdx.y;
  const int tid = threadIdx.x, wv = tid >> 6, sr = tid & 63, seg = tid >> 6;
  const u16* arow = A + (long)(rt * 64 + sr) * K;
  const u16* brow = Bm + (long)(ct * 64 + sr) * K;
  f32x4 acc[4][2] = {};
  for (int k0 = 0; k0 < K; k0 += 64) {
    __syncthreads();
    stage32_b16(&As[sr * 72 + seg * 32], arow + k0 + seg * 32);
    stage32_b16(&Bs[sr * 72 + seg * 32], brow + k0 + seg * 32);
    __syncthreads();
    mfma_bk64(As, Bs, acc, wv, sr);
  }
  const int l15 = sr & 15, q = sr >> 4, ldc = gridDim.y * 64;
#pragma unroll
  for (int nt = 0; nt < 2; ++nt) {
    const int col = ct * 64 + wv * 32 + nt * 16 + l15;
#pragma unroll
    for (int mt = 0; mt < 4; ++mt)
#pragma unroll
      for (int r = 0; r < 4; ++r) {
        const long idx = (long)(rt * 64 + mt * 16 + q * 4 + r) * ldc + col;
        if (OUTB16) ((u16*)C)[idx] = f2b(acc[mt][nt][r]);
        else        ((float*)C)[idx] = acc[mt][nt][r];
      }
  }
}

// ---------- decoder gates GEMM + cell (A = [y_emb | o_prev | h], K=2560) ----------
__global__ __launch_bounds__(128) void k_dec_gates(
    const int* tgt_tok, const float* demb, const u16* o_b16, const u16* hd,
    const u16* Wcat, const float* bih, const float* bhh,
    u16* hd_n, float* h2f, float* c_d, int t) {
  __shared__ short As[64 * 72], Bs[64 * 72];
  __shared__ float gsh[64 * 65];
  const int j0 = blockIdx.x * 16;
  const int tid = threadIdx.x, wv = tid >> 6, sr = tid & 63, seg = tid >> 6;
  const int token = tgt_tok[t * BBm + sr];
  const float* yrow = demb + (long)token * EEm;
  const int colg = (sr >> 4) * HHm + j0 + (sr & 15);
  const u16* brow = Wcat + (long)colg * 2560;
  f32x4 acc[4][2] = {};
  for (int k0 = 0; k0 < 2560; k0 += 64) {
    __syncthreads();
    {
      const int kk = k0 + seg * 32;
      short* dst = &As[sr * 72 + seg * 32];
      if (kk < 512)       stage32_f32(dst, yrow + kk);
      else if (kk < 1536) stage32_b16(dst, o_b16 + sr * HHm + (kk - 512));
      else                stage32_b16(dst, hd + sr * HHm + (kk - 1536));
    }
    stage32_b16(&Bs[sr * 72 + seg * 32], brow + k0 + seg * 32);
    __syncthreads();
    mfma_bk64(As, Bs, acc, wv, sr);
  }
  __syncthreads();
  const int l15 = sr & 15, q = sr >> 4;
#pragma unroll
  for (int nt = 0; nt < 2; ++nt) {
    const int c = wv * 32 + nt * 16 + l15;
    const int g = (c >> 4) * HHm + j0 + (c & 15);
    const float bias = bih[g] + bhh[g];
#pragma unroll
    for (int mt = 0; mt < 4; ++mt)
#pragma unroll
      for (int r = 0; r < 4; ++r)
        gsh[(mt * 16 + q * 4 + r) * 65 + c] = acc[mt][nt][r] + bias;
  }
  __syncthreads();
  const int jj = tid & 15, bq = tid >> 4;
#pragma unroll
  for (int u = 0; u < 8; ++u) {
    const int b = u * 8 + bq, j = j0 + jj;
    float gi = gsh[b * 65 + jj], gf = gsh[b * 65 + 16 + jj];
    float gg = gsh[b * 65 + 32 + jj], go = gsh[b * 65 + 48 + jj];
    float cold = c_d[b * HHm + j];
    float c2 = sigm(gf) * cold + sigm(gi) * tanh_(gg);
    float h2 = sigm(go) * tanh_(c2);
    c_d[b * HHm + j] = c2;
    hd_n[b * HHm + j] = f2b(h2);
    h2f[b * HHm + j] = h2;
  }
}

// ---------- attention (one block per batch row) ----------
__global__ __launch_bounds__(256) void k_att(const float* h2f, const u16* eproj,
                                             const u16* ench, const int* lens,
                                             u16* a_b16) {
  __shared__ float h2s[1024];
  __shared__ float part[256];
  __shared__ float alph[64];
  const int b = blockIdx.x, tid = threadIdx.x;
  *(f32x4*)&h2s[tid * 4] = *(const f32x4*)&h2f[b * 1024 + tid * 4];
  __syncthreads();
  {  // scores e[t'] = enc_proj[b,t',:] . h2
    const int tt = tid >> 2, qq = tid & 3;
    const u16* row = eproj + ((long)b * 64 + tt) * 1024 + qq * 256;
    float acc = 0.0f;
    for (int i = 0; i < 256; i += 8) {
      uint4v v = *(const uint4v*)(row + i);
      const u16* pv = (const u16*)&v;
#pragma unroll
      for (int j = 0; j < 8; ++j) acc += b2f(pv[j]) * h2s[qq * 256 + i + j];
    }
    part[tid] = acc;
  }
  __syncthreads();
  if (tid < 64) {
    float e = part[tid * 4] + part[tid * 4 + 1] + part[tid * 4 + 2] + part[tid * 4 + 3];
    e = (tid < lens[b]) ? e : -INFINITY;
    float mx = e;
#pragma unroll
    for (int m = 1; m < 64; m <<= 1) mx = fmaxf(mx, __shfl_xor(mx, m));
    float p = __expf(e - mx);
    float s = p;
#pragma unroll
    for (int m = 1; m < 64; m <<= 1) s += __shfl_xor(s, m);
    alph[tid] = p / s;
  }
  __syncthreads();
  {  // a = sum_t alpha[t] * enc_h[b,t,:]
    const int c0 = tid * 8;
    float acc[8] = {};
    for (int tt = 0; tt < 64; ++tt) {
      const float al = alph[tt];
      if (al == 0.0f) continue;
      uint4v v = *(const uint4v*)(ench + ((long)b * 64 + tt) * 2048 + c0);
      const u16* pv = (const u16*)&v;
#pragma unroll
      for (int j = 0; j < 8; ++j) acc[j] += al * b2f(pv[j]);
    }
    u16 outv[8];
#pragma unroll
    for (int j = 0; j < 8; ++j) outv[j] = f2b(acc[j]);
    *(uint4v*)&a_b16[b * 2048 + c0] = *(uint4v*)outv;
  }
}

// ---------- combine GEMM (split-K over 8 chunks of 384): O_pre = [a|h2] @ W_comb^T ----------
__global__ __launch_bounds__(128) void k_combine(const u16* a_b16, const float* h2f,
                                                 const u16* Wcomb, float* o_part) {
  __shared__ short As[64 * 72], Bs[64 * 72];
  const int ct = blockIdx.x, kc = blockIdx.y;
  const int tid = threadIdx.x, wv = tid >> 6, sr = tid & 63, seg = tid >> 6;
  const u16* arow_a = a_b16 + sr * 2048;
  const float* arow_h = h2f + sr * 1024;
  const u16* brow = Wcomb + (long)(ct * 64 + sr) * 3072;
  f32x4 acc[4][2] = {};
  for (int kl = 0; kl < 384; kl += 64) {
    const int k0 = kc * 384 + kl;
    __syncthreads();
    {
      const int kk = k0 + seg * 32;
      short* dst = &As[sr * 72 + seg * 32];
      if (kk < 2048) stage32_b16(dst, arow_a + kk);
      else           stage32_f32(dst, arow_h + (kk - 2048));
    }
    stage32_b16(&Bs[sr * 72 + seg * 32], brow + k0 + seg * 32);
    __syncthreads();
    mfma_bk64(As, Bs, acc, wv, sr);
  }
  const int l15 = sr & 15, q = sr >> 4;
#pragma unroll
  for (int nt = 0; nt < 2; ++nt) {
    const int col = ct * 64 + wv * 32 + nt * 16 + l15;
#pragma unroll
    for (int mt = 0; mt < 4; ++mt)
#pragma unroll
      for (int r = 0; r < 4; ++r)
        o_part[((long)kc * 64 + mt * 16 + q * 4 + r) * 1024 + col] = acc[mt][nt][r];
  }
}

__global__ void k_finish(const float* o_part, u16* o_b16, u16* outs, int t) {
  const int i = blockIdx.x * blockDim.x + threadIdx.x;  // 65536
  float v = 0.0f;
#pragma unroll
  for (int kc = 0; kc < 8; ++kc) v += o_part[kc * 65536 + i];
  const u16 h = f2b(tanh_(v));
  o_b16[i] = h;
  outs[(long)t * 65536 + i] = h;
}

// ---------- vocab projection: streaming sum(exp(logit)) ----------
__global__ __launch_bounds__(128) void k_vocab(const u16* outs, const u16* Wvoc,
                                               float* sumexp) {
  __shared__ short As[64 * 72], Bs[64 * 72];
  const int vt = blockIdx.x, t = blockIdx.y;
  const int tid = threadIdx.x, wv = tid >> 6, sr = tid & 63, seg = tid >> 6;
  const u16* arow = outs + ((long)t * 64 + sr) * 1024;
  const u16* brow = Wvoc + (long)(vt * 64 + sr) * 1024;
  f32x4 acc[4][2] = {};
  for (int k0 = 0; k0 < 1024; k0 += 64) {
    __syncthreads();
    stage32_b16(&As[sr * 72 + seg * 32], arow + k0 + seg * 32);
    stage32_b16(&Bs[sr * 72 + seg * 32], brow + k0 + seg * 32);
    __syncthreads();
    mfma_bk64(As, Bs, acc, wv, sr);
  }
  const int l15 = sr & 15, q = sr >> 4;
#pragma unroll
  for (int mt = 0; mt < 4; ++mt)
#pragma unroll
    for (int r = 0; r < 4; ++r) {
      float e = __expf(acc[mt][0][r]) + __expf(acc[mt][1][r]);
      e += __shfl_xor(e, 1); e += __shfl_xor(e, 2);
      e += __shfl_xor(e, 4); e += __shfl_xor(e, 8);
      if (l15 == 0) atomicAdd(&sumexp[t * 64 + mt * 16 + q * 4 + r], e);
    }
}

__global__ __launch_bounds__(256) void k_gold(const u16* outs, const u16* Wvoc,
                                              const int* tgt, float* gold) {
  const int t = blockIdx.x;
  const int wv = threadIdx.x >> 6, ln = threadIdx.x & 63;
  for (int b = wv; b < 64; b += 4) {
    const int g = tgt[(t + 1) * 64 + b];
    const u16* o = outs + ((long)t * 64 + b) * 1024 + ln * 16;
    const u16* w = Wvoc + (long)g * 1024 + ln * 16;
    uint4v v0 = *(const uint4v*)o, v1 = *(const uint4v*)(o + 8);
    uint4v w0 = *(const uint4v*)w, w1 = *(const uint4v*)(w + 8);
    const u16 *pv0 = (const u16*)&v0, *pv1 = (const u16*)&v1;
    const u16 *pw0 = (const u16*)&w0, *pw1 = (const u16*)&w1;
    float acc = 0.0f;
#pragma unroll
    for (int j = 0; j < 8; ++j)
      acc += b2f(pv0[j]) * b2f(pw0[j]) + b2f(pv1[j]) * b2f(pw1[j]);
#pragma unroll
    for (int m = 1; m < 64; m <<= 1) acc += __shfl_xor(acc, m);
    if (ln == 0) gold[t * 64 + b] = acc;
  }
}

__global__ void k_final(const float* gold, const float* sumexp, const int* tgt,
                        float* out) {
  const int b = threadIdx.x;
  float s = 0.0f;
  for (int t = 0; t < TDm; ++t)
    if (tgt[(t + 1) * 64 + b] != 0)
      s += gold[t * 64 + b] - logf(sumexp[t * 64 + b]);
  out[b] = s;
}

// ---------- host ----------
extern "C" void kernel_launch(void* const* d_in, const int* in_sizes, int n_in,
                              void* d_out, int out_size, void* d_ws, size_t ws_size,
                              hipStream_t stream) {
  const int* src_tok = (const int*)d_in[0];
  const int* tgt_tok = (const int*)d_in[1];
  const int* lens    = (const int*)d_in[2];
  const float* semb  = (const float*)d_in[3];
  const float* demb  = (const float*)d_in[4];
  const float* Wihf  = (const float*)d_in[5];
  const float* Whhf  = (const float*)d_in[6];
  const float* bihf  = (const float*)d_in[7];
  const float* bhhf  = (const float*)d_in[8];
  const float* Wihb  = (const float*)d_in[9];
  const float* Whhb  = (const float*)d_in[10];
  const float* bihb  = (const float*)d_in[11];
  const float* bhhb  = (const float*)d_in[12];
  const float* Wihd  = (const float*)d_in[13];
  const float* Whhd  = (const float*)d_in[14];
  const float* bihd  = (const float*)d_in[15];
  const float* bhhd  = (const float*)d_in[16];
  const float* Whp   = (const float*)d_in[17];
  const float* Wcp   = (const float*)d_in[18];
  const float* Watt  = (const float*)d_in[19];
  const float* Wcomb = (const float*)d_in[20];
  const float* Wvoc  = (const float*)d_in[21];

  char* w = (char*)d_ws;
  auto alloc = [&](size_t bytes) { char* p = w; w += (bytes + 255) & ~(size_t)255; return p; };
  // zero-span (contiguous): c_f, c_b, h_f(x2), h_b(x2), o_b, sumexp
  float* c_f  = (float*)alloc(262144);
  float* c_b  = (float*)alloc(262144);
  u16* h_f    = (u16*)alloc(262144);   // 2 ping-pong buffers
  u16* h_b    = (u16*)alloc(262144);
  u16* o_b    = (u16*)alloc(131072);
  float* sume = (float*)alloc(16128);
  const int zero16 = (int)(((char*)sume + 16128 - (char*)c_f) / 16);  // 74729
  float* gold   = (float*)alloc(16128);
  float* c_d    = (float*)alloc(262144);
  u16* h_d      = (u16*)alloc(262144);  // 2 ping-pong buffers
  float* h2f    = (float*)alloc(262144);
  u16* a_b      = (u16*)alloc(262144);
  u16* hcat     = (u16*)alloc(262144);
  u16* ccat     = (u16*)alloc(262144);
  float* o_part = (float*)alloc(2097152);
  u16* Wb_ihf   = (u16*)alloc(4194304);
  u16* Wb_ihb   = (u16*)alloc(4194304);
  u16* Wb_hhf   = (u16*)alloc(8388608);
  u16* Wb_hhb   = (u16*)alloc(8388608);
  u16* Wb_cat   = (u16*)alloc(20971520);
  u16* Wb_att   = (u16*)alloc(4194304);
  u16* Wb_hp    = (u16*)alloc(4194304);
  u16* Wb_cp    = (u16*)alloc(4194304);
  u16* Wb_comb  = (u16*)alloc(6291456);
  u16* Wb_voc   = (u16*)alloc(65536000);
  u16* pre_f    = (u16*)alloc(33554432);
  u16* pre_b    = (u16*)alloc(33554432);
  u16* ench     = (u16*)alloc(16777216);  // (b, t, 2048) bf16
  u16* eproj    = (u16*)alloc(8388608);   // (b, t, 1024) bf16
  u16* outs     = (u16*)alloc(8257536);   // (t, b, 1024) bf16

  k_zero<<<dim3(256), dim3(256), 0, stream>>>((uint4v*)c_f, zero16);
  k_cvt_all<<<dim3(2048), dim3(256), 0, stream>>>(
      Wihf, Wihb, Whhf, Whhb, Wihd, Whhd, Watt, Whp, Wcp, Wcomb, Wvoc,
      Wb_ihf, Wb_ihb, Wb_hhf, Wb_hhb, Wb_cat, Wb_att, Wb_hp, Wb_cp, Wb_comb, Wb_voc);
  k_pre_enc<<<dim3(64, 64, 2), dim3(128), 0, stream>>>(
      src_tok, semb, Wb_ihf, Wb_ihb, bihf, bhhf, bihb, bhhb, pre_f, pre_b);
  for (int s = 0; s < 64; ++s)
    k_enc_step<<<dim3(128), dim3(128), 0, stream>>>(
        Wb_hhf, Wb_hhb, pre_f, pre_b, lens, h_f, h_b, c_f, c_b, ench, s);
  // final states land in buffer 0 after step 63
  k_cat<<<dim3(256), dim3(256), 0, stream>>>(h_f, h_b, c_f, c_b, hcat, ccat);
  k_gemm_plain<true><<<dim3(1, 16), dim3(128), 0, stream>>>(hcat, Wb_hp, (void*)h_d, 2048);
  k_gemm_plain<false><<<dim3(1, 16), dim3(128), 0, stream>>>(ccat, Wb_cp, (void*)c_d, 2048);
  k_gemm_plain<true><<<dim3(64, 16), dim3(128), 0, stream>>>(ench, Wb_att, (void*)eproj, 2048);
  for (int t = 0; t < TDm; ++t) {
    const u16* hd_c = h_d + (t & 1) * 65536;
    u16* hd_n = h_d + ((t & 1) ^ 1) * 65536;
    k_dec_gates<<<dim3(64), dim3(128), 0, stream>>>(
        tgt_tok, demb, o_b, hd_c, Wb_cat, bihd, bhhd, hd_n, h2f, c_d, t);
    k_att<<<dim3(64), dim3(256), 0, stream>>>(h2f, eproj, ench, lens, a_b);
    k_combine<<<dim3(16, 8), dim3(128), 0, stream>>>(a_b, h2f, Wb_comb, o_part);
    k_finish<<<dim3(256), dim3(256), 0, stream>>>(o_part, o_b, outs, t);
  }
  k_vocab<<<dim3(500, 63), dim3(128), 0, stream>>>(outs, Wb_voc, sume);
  k_gold<<<dim3(63), dim3(256), 0, stream>>>(outs, Wb_voc, tgt_tok, gold);
  k_final<<<dim3(1), dim3(64), 0, stream>>>(gold, sume, tgt_tok, (float*)d_out);
}